// Round 8
// baseline (179.709 us; speedup 1.0000x reference)
//
#include <hip/hip_runtime.h>
#include <math.h>

#define E_DIM 512
#define H_DIM 8
#define WIN 128
#define L_SEQ 4096
#define B_SZ 2

typedef unsigned short ushort_t;
typedef unsigned int uint_t;
typedef __attribute__((ext_vector_type(8))) __bf16 bf16x8;
typedef __attribute__((ext_vector_type(4))) float f32x4;

// ---------- bf16 helpers (manual, RNE) ----------
__device__ __forceinline__ ushort_t f2bf(float f) {
    uint_t u = __float_as_uint(f);
    u = u + 0x7fffu + ((u >> 16) & 1u);
    return (ushort_t)(u >> 16);
}
__device__ __forceinline__ float bf2f(ushort_t h) {
    return __uint_as_float((uint_t)h << 16);
}

__device__ __forceinline__ void gload16(const ushort_t* g, ushort_t* l) {
    __builtin_amdgcn_global_load_lds(
        (const __attribute__((address_space(1))) void*)g,
        (__attribute__((address_space(3))) void*)l,
        16, 0, 0);
}

// ===== Tile image (16 rows x 32 k = 512 elems = 1 KB) =====
// idx = slot*8 + (k&7), slot = ((k>>3)&3)*16 + (row&15)
// A-frag & B-frag both read at lane*8 within a tile image.

// ---------- split-convert into tiled layout (x, w1, w2; all K=512) ----------
__global__ __launch_bounds__(256) void convert3(
    const float* __restrict__ x,  ushort_t* __restrict__ xh,  ushort_t* __restrict__ xl,
    const float* __restrict__ w1, ushort_t* __restrict__ w1h, ushort_t* __restrict__ w1l,
    const float* __restrict__ w2, ushort_t* __restrict__ w2h, ushort_t* __restrict__ w2l) {
    int sg = blockIdx.x * 256 + threadIdx.x;
    const float* src; ushort_t* dh; ushort_t* dl;
    if (sg < 524288)      { src = x;  dh = xh;  dl = xl; }
    else if (sg < 622592) { src = w1; dh = w1h; dl = w1l; sg -= 524288; }
    else                  { src = w2; dh = w2h; dl = w2l; sg -= 622592; }
    const int tile = sg >> 6, slot = sg & 63;
    const int row = (tile >> 4) * 16 + (slot & 15);
    const int k   = (tile & 15) * 32 + (slot >> 4) * 8;
    const float4 v0 = *(const float4*)&src[(size_t)row * 512 + k];
    const float4 v1 = *(const float4*)&src[(size_t)row * 512 + k + 4];
    const float vv[8] = {v0.x, v0.y, v0.z, v0.w, v1.x, v1.y, v1.z, v1.w};
    union { ushort_t u[8]; ushort4 v[2]; } h, l;
    #pragma unroll
    for (int j = 0; j < 8; j++) {
        const ushort_t a = f2bf(vv[j]);
        h.u[j] = a;
        l.u[j] = f2bf(vv[j] - bf2f(a));
    }
    ((ushort4*)(dh + (size_t)sg * 8))[0] = h.v[0];
    ((ushort4*)(dh + (size_t)sg * 8))[1] = h.v[1];
    ((ushort4*)(dl + (size_t)sg * 8))[0] = l.v[0];
    ((ushort4*)(dl + (size_t)sg * 8))[1] = l.v[1];
}

// ---------- GEMM1: qkv projection, epilogue writes attention-ready layouts ----
// 128x128 tile, BK=32. 1D grid 768, XCD-swizzled: xcd=bid&7 owns row-stripes
// [8*xcd, 8*xcd+8); its 96 jobs iterate cols-fastest so A stays in that XCD's L2.
__global__ __launch_bounds__(256) void gemm_qkv(
    const ushort_t* __restrict__ Ah, const ushort_t* __restrict__ Al,
    const ushort_t* __restrict__ Wh, const ushort_t* __restrict__ Wl,
    const float* __restrict__ bias,
    ushort_t* __restrict__ qTh, ushort_t* __restrict__ qTl,
    ushort_t* __restrict__ kTh, ushort_t* __restrict__ kTl,
    ushort_t* __restrict__ vTh) {
    __shared__ __align__(16) ushort_t sAh[8 * 512];
    __shared__ __align__(16) ushort_t sAl[8 * 512];
    __shared__ __align__(16) ushort_t sWh[8 * 512];
    __shared__ __align__(16) ushort_t sWl[8 * 512];

    const int tid = threadIdx.x, lane = tid & 63, w = tid >> 6;
    const int wm = w & 1, wn = w >> 1, ln = lane & 15, quad = lane >> 4;
    // XCD-aware decode: bid&7 = XCD (round-robin dispatch heuristic)
    const int bid = blockIdx.x;
    const int jj = bid >> 3, xcd = bid & 7;
    const int bx = xcd * 8 + jj / 12;   // row-stripe 0..63
    const int by = jj % 12;             // col-block 0..11
    const int lo8 = lane * 8;

    f32x4 acc[4][4];
    const f32x4 zero = {0.f, 0.f, 0.f, 0.f};
    #pragma unroll
    for (int i = 0; i < 4; i++)
        #pragma unroll
        for (int j = 0; j < 4; j++) acc[i][j] = zero;

    const ushort_t* aSrc = (w & 2) ? Al : Ah;
    ushort_t* aDst = (w & 2) ? sAl : sAh;
    const ushort_t* wSrc = (w & 2) ? Wl : Wh;
    ushort_t* wDst = (w & 2) ? sWl : sWh;
    const int at0 = (w & 1) * 4, wt0 = (w & 1) * 4;

    const ushort_t* pa[4];
    const ushort_t* pw[4];
    #pragma unroll
    for (int t = 0; t < 4; t++) {
        pa[t] = aSrc + ((size_t)(bx * 8 + at0 + t) * 16) * 512;
        pw[t] = wSrc + ((size_t)(by * 8 + wt0 + t) * 16) * 512;
    }

    for (int kt = 0; kt < 16; kt++) {
        const int koff = kt * 512;
        __syncthreads();
        #pragma unroll
        for (int t = 0; t < 4; t++)
            gload16(pa[t] + koff + lo8, &aDst[(at0 + t) * 512]);
        #pragma unroll
        for (int t = 0; t < 4; t++)
            gload16(pw[t] + koff + lo8, &wDst[(wt0 + t) * 512]);
        __syncthreads();

        const int foff = lo8;
        bf16x8 fah[4], fal[4];
        #pragma unroll
        for (int i = 0; i < 4; i++) {
            fah[i] = *(const bf16x8*)&sAh[(wm * 4 + i) * 512 + foff];
            fal[i] = *(const bf16x8*)&sAl[(wm * 4 + i) * 512 + foff];
        }
        #pragma unroll
        for (int j = 0; j < 4; j++) {
            const bf16x8 fbh = *(const bf16x8*)&sWh[(wn * 4 + j) * 512 + foff];
            const bf16x8 fbl = *(const bf16x8*)&sWl[(wn * 4 + j) * 512 + foff];
            #pragma unroll
            for (int i = 0; i < 4; i++) {
                acc[i][j] = __builtin_amdgcn_mfma_f32_16x16x32_bf16(fah[i], fbh, acc[i][j], 0, 0, 0);
                acc[i][j] = __builtin_amdgcn_mfma_f32_16x16x32_bf16(fah[i], fbl, acc[i][j], 0, 0, 0);
                acc[i][j] = __builtin_amdgcn_mfma_f32_16x16x32_bf16(fal[i], fbh, acc[i][j], 0, 0, 0);
            }
        }
    }

    // ---- epilogue: C/D layout col=ln (within j-tile), row=quad*4+r ----
    const int b = bx >> 5;               // batch
    const int h = 2 * (by & 3) + wn;     // head (wave-uniform)
    if (by < 8) {
        ushort_t* dh = (by < 4) ? qTh : kTh;
        ushort_t* dl = (by < 4) ? qTl : kTl;
        #pragma unroll
        for (int i = 0; i < 4; i++) {
            const int rt = (bx & 31) * 8 + wm * 4 + i;   // row-tile within batch
            const size_t tb = ((size_t)(b * 8 + h) * 256 + rt) * 2;
            #pragma unroll
            for (int j = 0; j < 4; j++) {
                const float bv = bias[by * 128 + wn * 64 + j * 16 + ln];
                const size_t tile = tb + (j >> 1);
                #pragma unroll
                for (int r = 0; r < 4; r++) {
                    const int slot = ((j * 2 + (ln >> 3)) & 3) * 16 + quad * 4 + r;
                    const size_t idx = tile * 512 + slot * 8 + (ln & 7);
                    const float v = acc[i][j][r] + bv;
                    const ushort_t hh = f2bf(v);
                    dh[idx] = hh;
                    dl[idx] = f2bf(v - bf2f(hh));
                }
            }
        }
    } else {
        // v: hi only, transposed tiles (rows = d, k = kseq)
        const int kwin = (bx & 31) * 2 + wm;
        #pragma unroll
        for (int i = 0; i < 4; i++) {
            const int kk = i >> 1;
            #pragma unroll
            for (int j = 0; j < 4; j++) {
                const float bv = bias[by * 128 + wn * 64 + j * 16 + ln];
                const size_t tile = (((size_t)(b * 8 + h) * 64 + kwin) * 4 + j) * 2 + kk;
                #pragma unroll
                for (int r = 0; r < 4; r++) {
                    const int klq = quad * 4 + r;
                    const int slot = ((i & 1) * 2 + (klq >> 3)) * 16 + ln;
                    const size_t idx = tile * 512 + slot * 8 + (klq & 7);
                    vTh[idx] = f2bf(acc[i][j][r] + bv);
                }
            }
        }
    }
}

// ---------- MFMA windowed attention: all operands pre-tiled ----------
// 1D grid 1024, XCD-swizzled: each XCD owns 2 (b,h) pairs x 64 q-tiles so
// the K/V window reuse across neighboring q-tiles stays in one XCD's L2.
__global__ __launch_bounds__(256) void attn_mfma(
    const ushort_t* __restrict__ qTh, const ushort_t* __restrict__ qTl,
    const ushort_t* __restrict__ kTh, const ushort_t* __restrict__ kTl,
    const ushort_t* __restrict__ vTh,
    ushort_t* __restrict__ outh, ushort_t* __restrict__ outl) {
    __shared__ __align__(16) ushort_t sKh[8 * 512];
    __shared__ __align__(16) ushort_t sKl[8 * 512];
    __shared__ __align__(16) ushort_t sV [8 * 512];
    __shared__ __align__(16) ushort_t sP [8 * 512];

    const int bid = blockIdx.x;
    const int xcd = bid & 7, jj = bid >> 3;      // jj 0..127
    const int bh = xcd * 2 + (jj >> 6);          // 0..15
    const int b = bh >> 3, h = bh & 7;
    const int qs = (jj & 63) * 64;
    const int tid = threadIdx.x, lane = tid & 63;
    const int w = tid >> 6, ln = lane & 15, quad = lane >> 4;
    const int lo8 = lane * 8;

    // Q fragments: direct global loads from A-frag tiles
    bf16x8 qf[2][2];
    {
        const size_t qt = ((size_t)bh * 256 + (qs >> 4) + w) * 2;
        qf[0][0] = *(const bf16x8*)(qTh + (qt + 0) * 512 + lo8);
        qf[1][0] = *(const bf16x8*)(qTh + (qt + 1) * 512 + lo8);
        qf[0][1] = *(const bf16x8*)(qTl + (qt + 0) * 512 + lo8);
        qf[1][1] = *(const bf16x8*)(qTl + (qt + 1) * 512 + lo8);
    }

    f32x4 oacc[4];
    const f32x4 zero = {0.f, 0.f, 0.f, 0.f};
    #pragma unroll
    for (int dt = 0; dt < 4; dt++) oacc[dt] = zero;
    float m_run[4], l_run[4];
    #pragma unroll
    for (int r = 0; r < 4; r++) { m_run[r] = -1e30f; l_run[r] = 0.f; }

    const float cscale = 0.125f * 1.44269504f;  // 1/sqrt(D) * log2(e)

    for (int kt = 0; kt < 5; kt++) {
        const int ks = qs - 128 + kt * 64;

        __syncthreads();  // prev iter's MFMA reads of sK/sV/sP done

        // stage K (jt = w) and V (dt = w), clamped tile indices
        {
            int st = (qs >> 4) - 8 + kt * 4 + w;
            st = st < 0 ? 0 : (st > 255 ? 255 : st);
            const size_t kb = ((size_t)bh * 256 + st) * 2 * 512 + lo8;
            gload16(kTh + kb,       &sKh[(w * 2 + 0) * 512]);
            gload16(kTh + kb + 512, &sKh[(w * 2 + 1) * 512]);
            gload16(kTl + kb,       &sKl[(w * 2 + 0) * 512]);
            gload16(kTl + kb + 512, &sKl[(w * 2 + 1) * 512]);
            int vw = (qs >> 6) - 2 + kt;
            vw = vw < 0 ? 0 : (vw > 63 ? 63 : vw);
            const size_t vb = (((size_t)bh * 64 + vw) * 4 + w) * 2 * 512 + lo8;
            gload16(vTh + vb,       &sV[(w * 2 + 0) * 512]);
            gload16(vTh + vb + 512, &sV[(w * 2 + 1) * 512]);
        }
        __syncthreads();  // staging visible

        // S = Q K^T (hh + hl + lh)
        f32x4 sacc[4];
        #pragma unroll
        for (int jt = 0; jt < 4; jt++) {
            f32x4 a = zero;
            const bool dead = (kt == 0 && jt < w) || (kt == 4 && jt > w) ||
                              (ks + 16 * jt >= L_SEQ) || (ks + 16 * jt + 15 < 0);
            if (!dead) {
                #pragma unroll
                for (int kk = 0; kk < 2; kk++) {
                    const bf16x8 kh = *(const bf16x8*)&sKh[(jt * 2 + kk) * 512 + lo8];
                    const bf16x8 klo = *(const bf16x8*)&sKl[(jt * 2 + kk) * 512 + lo8];
                    a = __builtin_amdgcn_mfma_f32_16x16x32_bf16(qf[kk][0], kh, a, 0, 0, 0);
                    a = __builtin_amdgcn_mfma_f32_16x16x32_bf16(qf[kk][0], klo, a, 0, 0, 0);
                    a = __builtin_amdgcn_mfma_f32_16x16x32_bf16(qf[kk][1], kh, a, 0, 0, 0);
                }
            }
            sacc[jt] = a;
        }

        // mask + online softmax (registers)
        float u[4][4];
        #pragma unroll
        for (int jt = 0; jt < 4; jt++) {
            const int kcol = ks + 16 * jt + ln;
            #pragma unroll
            for (int r = 0; r < 4; r++) {
                const int qrow = qs + 16 * w + quad * 4 + r;
                const int dist = qrow > kcol ? qrow - kcol : kcol - qrow;
                const bool ok = (kcol >= 0) && (kcol < L_SEQ) && (dist >= 1) && (dist <= WIN);
                u[jt][r] = ok ? sacc[jt][r] * cscale : -INFINITY;
            }
        }
        float mk[4];
        #pragma unroll
        for (int r = 0; r < 4; r++)
            mk[r] = fmaxf(fmaxf(u[0][r], u[1][r]), fmaxf(u[2][r], u[3][r]));
        #pragma unroll
        for (int off = 1; off <= 8; off <<= 1)
            #pragma unroll
            for (int r = 0; r < 4; r++)
                mk[r] = fmaxf(mk[r], __shfl_xor(mk[r], off));

        float alpha[4], psum[4], p[4][4];
        #pragma unroll
        for (int r = 0; r < 4; r++) {
            const float mnew = fmaxf(fmaxf(m_run[r], mk[r]), -1e30f);
            alpha[r] = exp2f(m_run[r] - mnew);
            m_run[r] = mnew;
            psum[r] = 0.f;
            #pragma unroll
            for (int jt = 0; jt < 4; jt++) {
                p[jt][r] = exp2f(u[jt][r] - mnew);
                psum[r] += p[jt][r];
            }
        }
        #pragma unroll
        for (int off = 1; off <= 8; off <<= 1)
            #pragma unroll
            for (int r = 0; r < 4; r++)
                psum[r] += __shfl_xor(psum[r], off);
        #pragma unroll
        for (int r = 0; r < 4; r++)
            l_run[r] = l_run[r] * alpha[r] + psum[r];

        #pragma unroll
        for (int dt = 0; dt < 4; dt++)
            #pragma unroll
            for (int r = 0; r < 4; r++)
                oacc[dt][r] *= alpha[r];

        // P (hi only): C-layout regs -> own wave's A-frag tile images in LDS
        #pragma unroll
        for (int jt = 0; jt < 4; jt++)
            #pragma unroll
            for (int r = 0; r < 4; r++) {
                const int slot = ((jt & 1) * 2 + (ln >> 3)) * 16 + quad * 4 + r;
                sP[w * 1024 + (jt >> 1) * 512 + slot * 8 + (ln & 7)] = f2bf(p[jt][r]);
            }
        // no barrier needed: PV reads only this wave's sP region + sV (staged pre-barrier)

        // O += P V (hi x hi)
        #pragma unroll
        for (int kk = 0; kk < 2; kk++) {
            const bf16x8 pf = *(const bf16x8*)&sP[w * 1024 + kk * 512 + lo8];
            #pragma unroll
            for (int dt = 0; dt < 4; dt++) {
                const bf16x8 vf = *(const bf16x8*)&sV[(dt * 2 + kk) * 512 + lo8];
                oacc[dt] = __builtin_amdgcn_mfma_f32_16x16x32_bf16(pf, vf, oacc[dt], 0, 0, 0);
            }
        }
    }

    // epilogue: write split bf16 in GEMM2's A-frag tiled layout
    const int Rt = ((b * L_SEQ + qs) >> 4) + w;
    #pragma unroll
    for (int r = 0; r < 4; r++) {
        const float inv_l = 1.f / l_run[r];
        #pragma unroll
        for (int dt = 0; dt < 4; dt++) {
            const float v = oacc[dt][r] * inv_l;
            const ushort_t vh = f2bf(v);
            const int tile = Rt * 16 + h * 2 + (dt >> 1);
            const int slot = ((dt & 1) * 2 + (ln >> 3)) * 16 + quad * 4 + r;
            const size_t idx = (size_t)tile * 512 + slot * 8 + (ln & 7);
            outh[idx] = vh;
            outl[idx] = f2bf(v - bf2f(vh));
        }
    }
}

// ---------- GEMM2: out projection, 64x64 tile, 1D grid 1024 XCD-swizzled ----
__global__ __launch_bounds__(256) void gemm_out(
    const ushort_t* __restrict__ Ah, const ushort_t* __restrict__ Al,
    const ushort_t* __restrict__ Wh, const ushort_t* __restrict__ Wl,
    const float* __restrict__ bias, float* __restrict__ C) {
    __shared__ __align__(16) ushort_t sAh[4 * 512];
    __shared__ __align__(16) ushort_t sAl[4 * 512];
    __shared__ __align__(16) ushort_t sWh[4 * 512];
    __shared__ __align__(16) ushort_t sWl[4 * 512];

    const int tid = threadIdx.x, lane = tid & 63, w = tid >> 6;
    const int wm = w & 1, wn = w >> 1, ln = lane & 15, quad = lane >> 4;
    const int bid = blockIdx.x;
    const int jj = bid >> 3, xcd = bid & 7;
    const int bx = xcd * 16 + (jj >> 3);  // row-stripe 0..127
    const int by = jj & 7;                // col-block 0..7
    const int lo8 = lane * 8;

    f32x4 acc[2][2];
    const f32x4 zero = {0.f, 0.f, 0.f, 0.f};
    #pragma unroll
    for (int i = 0; i < 2; i++)
        #pragma unroll
        for (int j = 0; j < 2; j++) acc[i][j] = zero;

    // wave-uniform staging role: w0=A-hi, w1=A-lo, w2=W-hi, w3=W-lo
    const ushort_t* src = (w == 0) ? Ah : (w == 1) ? Al : (w == 2) ? Wh : Wl;
    ushort_t* dst = (w == 0) ? sAh : (w == 1) ? sAl : (w == 2) ? sWh : sWl;
    const size_t tbase = (size_t)((w < 2) ? bx : by) * 4 * 16;

    for (int kt = 0; kt < 16; kt++) {
        __syncthreads();
        #pragma unroll
        for (int t = 0; t < 4; t++)
            gload16(src + (tbase + (size_t)t * 16 + kt) * 512 + lo8, &dst[t * 512]);
        __syncthreads();

        bf16x8 fah[2], fal[2];
        #pragma unroll
        for (int i = 0; i < 2; i++) {
            fah[i] = *(const bf16x8*)&sAh[(wm * 2 + i) * 512 + lo8];
            fal[i] = *(const bf16x8*)&sAl[(wm * 2 + i) * 512 + lo8];
        }
        #pragma unroll
        for (int j = 0; j < 2; j++) {
            const bf16x8 fbh = *(const bf16x8*)&sWh[(wn * 2 + j) * 512 + lo8];
            const bf16x8 fbl = *(const bf16x8*)&sWl[(wn * 2 + j) * 512 + lo8];
            #pragma unroll
            for (int i = 0; i < 2; i++) {
                acc[i][j] = __builtin_amdgcn_mfma_f32_16x16x32_bf16(fah[i], fbh, acc[i][j], 0, 0, 0);
                acc[i][j] = __builtin_amdgcn_mfma_f32_16x16x32_bf16(fah[i], fbl, acc[i][j], 0, 0, 0);
                acc[i][j] = __builtin_amdgcn_mfma_f32_16x16x32_bf16(fal[i], fbh, acc[i][j], 0, 0, 0);
            }
        }
    }

    #pragma unroll
    for (int i = 0; i < 2; i++) {
        const int row0 = bx * 64 + wm * 32 + i * 16 + quad * 4;
        #pragma unroll
        for (int j = 0; j < 2; j++) {
            const int col = by * 64 + wn * 32 + j * 16 + ln;
            const float bv = bias[col];
            #pragma unroll
            for (int r = 0; r < 4; r++)
                C[(size_t)(row0 + r) * E_DIM + col] = acc[i][j][r] + bv;
        }
    }
}

extern "C" void kernel_launch(void* const* d_in, const int* in_sizes, int n_in,
                              void* d_out, int out_size, void* d_ws, size_t ws_size,
                              hipStream_t stream) {
    const float* x         = (const float*)d_in[0];
    const float* in_proj_w = (const float*)d_in[1];
    const float* in_proj_b = (const float*)d_in[2];
    const float* out_w     = (const float*)d_in[3];
    const float* out_b     = (const float*)d_in[4];
    float* out = (float*)d_out;

    const int N = B_SZ * L_SEQ;  // 8192
    const size_t NE = (size_t)N * E_DIM;  // 4.19M elems

    char* p = (char*)d_ws;
    ushort_t* xh  = (ushort_t*)p; p += NE * 2;
    ushort_t* xl  = (ushort_t*)p; p += NE * 2;
    ushort_t* w1h = (ushort_t*)p; p += (size_t)3 * E_DIM * E_DIM * 2;
    ushort_t* w1l = (ushort_t*)p; p += (size_t)3 * E_DIM * E_DIM * 2;
    ushort_t* w2h = (ushort_t*)p; p += (size_t)E_DIM * E_DIM * 2;
    ushort_t* w2l = (ushort_t*)p; p += (size_t)E_DIM * E_DIM * 2;
    ushort_t* qTh = (ushort_t*)p; p += NE * 2;
    ushort_t* qTl = (ushort_t*)p; p += NE * 2;
    ushort_t* kTh = (ushort_t*)p; p += NE * 2;
    ushort_t* kTl = (ushort_t*)p; p += NE * 2;
    ushort_t* vTh = (ushort_t*)p; p += NE * 2;
    ushort_t* ath = (ushort_t*)p; p += NE * 2;
    ushort_t* atl = (ushort_t*)p; p += NE * 2;
    // total ~79.7 MB

    convert3<<<2560, 256, 0, stream>>>(x, xh, xl, in_proj_w, w1h, w1l, out_w, w2h, w2l);

    gemm_qkv<<<768, 256, 0, stream>>>(
        xh, xl, w1h, w1l, in_proj_b, qTh, qTl, kTh, kTl, vTh);

    attn_mfma<<<1024, 256, 0, stream>>>(
        qTh, qTl, kTh, kTl, vTh, ath, atl);

    gemm_out<<<1024, 256, 0, stream>>>(
        ath, atl, w2h, w2l, out_b, out);
}